// Round 4
// baseline (744.948 us; speedup 1.0000x reference)
//
#include <hip/hip_runtime.h>
#include <hip/hip_bf16.h>

#define D 128

typedef unsigned short u16;
typedef unsigned int   u32;
typedef unsigned long long u64;
typedef short bf16x8 __attribute__((ext_vector_type(8)));
typedef float f32x4  __attribute__((ext_vector_type(4)));

__device__ __forceinline__ float bf2f(u16 u) {
    union { u32 i; float f; } v; v.i = ((u32)u) << 16; return v.f;
}
__device__ __forceinline__ float bflo(u32 p) {
    union { u32 i; float f; } v; v.i = p << 16; return v.f;
}
__device__ __forceinline__ float bfhi(u32 p) {
    union { u32 i; float f; } v; v.i = p & 0xffff0000u; return v.f;
}
__device__ __forceinline__ u16 f2bf(float f) {
    union { float f; u32 i; } v; v.f = f;
    return (u16)((v.i + 0x7fffu + ((v.i >> 16) & 1u)) >> 16);
}
__device__ __forceinline__ float ldf(const void* p, long i, int isb) {
    return isb ? bf2f(((const u16*)p)[i]) : ((const float*)p)[i];
}

__device__ __forceinline__ float sigm(float x) { return 1.0f / (1.0f + __expf(-x)); }
__device__ __forceinline__ float tanh_fast(float x) {
    float a = fabsf(x);
    float t = __expf(-2.0f * a);
    float r = (1.0f - t) / (1.0f + t);
    return copysignf(r, x);
}

__global__ void DRlocal_net_79173427135059_kernel() {}

// K-1: runtime dtype detection. flag[0]=inputs-are-bf16, flag[1]=node_id-is-int64.
__global__ __launch_bounds__(64) void k_detect(const void* ent, const void* nid, int* flag) {
    int lane = threadIdx.x;
    float a = fabsf(bf2f(((const u16*)ent)[lane]));
    bool sane = (a >= 9.765625e-4f && a <= 64.0f);
    u64 m = __ballot(sane);
    u32 w = ((const u32*)nid)[lane];
    bool oddzero = ((lane & 1) == 0) || (w == 0u);
    u64 m2 = __ballot(oddzero);
    if (lane == 0) {
        flag[0] = (__popcll(m) >= 48) ? 1 : 0;
        flag[1] = (m2 == ~0ull) ? 1 : 0;
    }
}

// K0: WTb[j][k] = bf16(W[k][j]); GRU weights -> bf16 as-is; biases -> f32.
__global__ __launch_bounds__(256) void k_prep(
    const void* __restrict__ w_ih, const void* __restrict__ w_hh,
    const void* __restrict__ b_ih, const void* __restrict__ b_hh,
    const void* __restrict__ W, const int* __restrict__ flag,
    u16* __restrict__ WTb, u16* __restrict__ Wihb, u16* __restrict__ Whhb,
    float* __restrict__ bif, float* __restrict__ bhf)
{
    int isb = flag[0];
    int t = blockIdx.x * 256 + threadIdx.x;
    if (t < 16384) {
        int k = t >> 7, j = t & 127;
        u16 v = isb ? ((const u16*)W)[t] : f2bf(((const float*)W)[t]);
        WTb[j * 128 + k] = v;
        return;
    }
    int u = t - 16384;
    if (u < 98304) { Wihb[u] = isb ? ((const u16*)w_ih)[u] : f2bf(((const float*)w_ih)[u]); return; }
    int v = u - 98304;
    if (v < 49152) { Whhb[v] = isb ? ((const u16*)w_hh)[v] : f2bf(((const float*)w_hh)[v]); return; }
    int b = v - 49152;
    if (b < 384) { bif[b] = ldf(b_ih, b, isb); return; }
    int c = b - 384;
    if (c < 384) { bhf[c] = ldf(b_hh, c, isb); return; }
}

__global__ __launch_bounds__(256) void k_zero(int* __restrict__ cnt, int n) {
    int t = blockIdx.x * 256 + threadIdx.x;
    if (t < n) cnt[t] = 0;
}

// K1: hW = gather(ent, node_id) @ W via MFMA. 64 nodes/block, wave = one 16-row m-tile.
// A-frags gathered straight to registers; B = WTb rows (L1-resident).
__global__ __launch_bounds__(256) void k_gmm_mfma(
    const void* __restrict__ ent, const void* __restrict__ node_id,
    const u16* __restrict__ WTb, u16* __restrict__ hW,
    const int* __restrict__ flag, int N)
{
    int isb = flag[0], i64 = flag[1];
    int tid = threadIdx.x;
    int wave = tid >> 6, lane = tid & 63;
    int qm = lane >> 4, qr = lane & 15;
    int row0 = blockIdx.x * 64 + wave * 16;

    int rowA = row0 + qr; if (rowA >= N) rowA = N - 1;
    long nid = i64 ? (long)((const long long*)node_id)[rowA]
                   : (long)((const int*)node_id)[rowA];

    // A[m=qr][k = s*32 + qm*8 + j]
    bf16x8 a[4];
    if (isb) {
        const u16* ep = (const u16*)ent + nid * 128 + qm * 8;
        #pragma unroll
        for (int s = 0; s < 4; ++s) a[s] = *(const bf16x8*)(ep + s * 32);
    } else {
        const float* ep = (const float*)ent + nid * 128 + qm * 8;
        #pragma unroll
        for (int s = 0; s < 4; ++s) {
            float4 f0 = *(const float4*)(ep + s * 32);
            float4 f1 = *(const float4*)(ep + s * 32 + 4);
            bf16x8 t;
            t[0] = (short)f2bf(f0.x); t[1] = (short)f2bf(f0.y);
            t[2] = (short)f2bf(f0.z); t[3] = (short)f2bf(f0.w);
            t[4] = (short)f2bf(f1.x); t[5] = (short)f2bf(f1.y);
            t[6] = (short)f2bf(f1.z); t[7] = (short)f2bf(f1.w);
            a[s] = t;
        }
    }

    int r0 = row0 + qm * 4;
    #pragma unroll
    for (int f = 0; f < 8; ++f) {
        f32x4 acc = {0.f, 0.f, 0.f, 0.f};
        const u16* wp = WTb + (size_t)(f * 16 + qr) * 128 + qm * 8;
        #pragma unroll
        for (int s = 0; s < 4; ++s) {
            bf16x8 b = *(const bf16x8*)(wp + s * 32);
            acc = __builtin_amdgcn_mfma_f32_16x16x32_bf16(a[s], b, acc, 0, 0, 0);
        }
        int col = f * 16 + qr;
        #pragma unroll
        for (int r = 0; r < 4; ++r) {
            int row = r0 + r;
            if (row < N) hW[(size_t)row * 128 + col] = f2bf(acc[r]);
        }
    }
}

// ---- CSR build ----
__global__ __launch_bounds__(256) void k_hist(
    const int* __restrict__ edst, int* __restrict__ cnt, int E)
{
    int e = blockIdx.x * 256 + threadIdx.x;
    if (e < E) atomicAdd(&cnt[edst[e]], 1);
}

__global__ __launch_bounds__(256) void k_scan1(
    const int* __restrict__ cnt, int* __restrict__ rowstart,
    int* __restrict__ part, int N)
{
    __shared__ int ssum[256];
    int b = blockIdx.x, t = threadIdx.x;
    int base = b * 1024 + t * 4;
    int v[4]; int s = 0;
    #pragma unroll
    for (int i = 0; i < 4; ++i) {
        int idx = base + i;
        v[i] = (idx < N) ? cnt[idx] : 0;
        s += v[i];
    }
    ssum[t] = s;
    __syncthreads();
    #pragma unroll
    for (int off = 1; off < 256; off <<= 1) {
        int x = (t >= off) ? ssum[t - off] : 0;
        __syncthreads();
        ssum[t] += x;
        __syncthreads();
    }
    int run = ssum[t] - s;
    #pragma unroll
    for (int i = 0; i < 4; ++i) {
        int idx = base + i;
        if (idx < N) rowstart[idx] = run;
        run += v[i];
    }
    if (t == 255) part[b] = ssum[255];
}

// Parallel 128-lane scan over the nb block partials (was single-threaded
// serial loop of dependent L2 reads, ~12 us).
__global__ __launch_bounds__(128) void k_scan2(
    int* __restrict__ part, int* __restrict__ rowstart, int nb, int N)
{
    __shared__ int sh[128];
    int t = threadIdx.x;
    int run = 0;
    for (int base = 0; base < nb; base += 128) {
        int i = base + t;
        int v = (i < nb) ? part[i] : 0;
        sh[t] = v;
        __syncthreads();
        #pragma unroll
        for (int off = 1; off < 128; off <<= 1) {
            int x = (t >= off) ? sh[t - off] : 0;
            __syncthreads();
            sh[t] += x;
            __syncthreads();
        }
        int incl = sh[t];
        if (i < nb) part[i] = run + incl - v;   // exclusive prefix
        int tot = sh[127];
        __syncthreads();
        run += tot;
    }
    if (t == 0) rowstart[N] = run;
}

__global__ __launch_bounds__(256) void k_scan3(
    int* __restrict__ rowstart, const int* __restrict__ part,
    int* __restrict__ cursor, int N)
{
    int t = blockIdx.x * 256 + threadIdx.x;
    if (t < N) {
        int r = rowstart[t] + part[t >> 10];
        rowstart[t] = r;
        cursor[t] = r;
    }
}

__global__ __launch_bounds__(256) void k_fill(
    const int* __restrict__ esrc, const int* __restrict__ edst,
    int* __restrict__ cursor, int* __restrict__ sorted_src, int E)
{
    int e = blockIdx.x * 256 + threadIdx.x;
    if (e < E) {
        int d = edst[e];
        int pos = atomicAdd(&cursor[d], 1);
        sorted_src[pos] = esrc[e];
    }
}

// K3: segment sum -> X[:,0:128] = bf16(agg*out_norm); also X[:,128:256] = e_r_bias.
// 8-deep gather unroll for MLP on the 410 MB edge gather.
__global__ __launch_bounds__(256) void k_seg(
    const u16* __restrict__ hW, const int* __restrict__ rowstart,
    const int* __restrict__ sorted_src, const void* __restrict__ onorm,
    const void* __restrict__ bias, u16* __restrict__ X,
    const int* __restrict__ flag, int N)
{
    int isb = flag[0];
    int tid = threadIdx.x;
    int node = blockIdx.x * 4 + (tid >> 6);
    int lane = tid & 63;
    if (node >= N) return;
    int beg = rowstart[node], end = rowstart[node + 1];
    const u32* hw2 = (const u32*)hW;
    float a0 = 0.f, a1 = 0.f;
    int e = beg;
    for (; e + 8 <= end; e += 8) {
        int sI[8]; u32 vI[8];
        #pragma unroll
        for (int i = 0; i < 8; ++i) sI[i] = sorted_src[e + i];
        #pragma unroll
        for (int i = 0; i < 8; ++i) vI[i] = hw2[(size_t)sI[i] * 64 + lane];
        #pragma unroll
        for (int i = 0; i < 8; ++i) { a0 += bflo(vI[i]); a1 += bfhi(vI[i]); }
    }
    for (; e + 4 <= end; e += 4) {
        int s0 = sorted_src[e], s1 = sorted_src[e + 1];
        int s2 = sorted_src[e + 2], s3 = sorted_src[e + 3];
        u32 v0 = hw2[(size_t)s0 * 64 + lane];
        u32 v1 = hw2[(size_t)s1 * 64 + lane];
        u32 v2 = hw2[(size_t)s2 * 64 + lane];
        u32 v3 = hw2[(size_t)s3 * 64 + lane];
        a0 += bflo(v0) + bflo(v1) + bflo(v2) + bflo(v3);
        a1 += bfhi(v0) + bfhi(v1) + bfhi(v2) + bfhi(v3);
    }
    for (; e < end; ++e) {
        u32 v = hw2[(size_t)sorted_src[e] * 64 + lane];
        a0 += bflo(v); a1 += bfhi(v);
    }
    float on = ldf(onorm, node, isb);
    u32 p = ((u32)f2bf(a1 * on) << 16) | (u32)f2bf(a0 * on);
    ((u32*)X)[(size_t)node * 128 + lane] = p;
    // bias half
    u32 pb;
    if (isb) pb = ((const u32*)bias)[(size_t)node * 64 + lane];
    else {
        const float* bp = (const float*)bias + (size_t)node * 128 + lane * 2;
        pb = ((u32)f2bf(bp[1]) << 16) | (u32)f2bf(bp[0]);
    }
    ((u32*)X)[(size_t)node * 128 + 64 + lane] = pb;
}

// K4 v4: wave-independent MFMA GRU. One wave = 16 rows x ALL 128 cols,
// looping 8 col-slices (fully unrolled; all arrays statically indexed).
// Weight frags are re-read from L2 per slice BY DESIGN (shared, hot across
// all 6250 waves) -- three rounds proved the allocator won't keep them
// resident. The L2 norm is in-wave: in-lane sum over 8 slices + shfl_xor
// over the 16 qr lanes. ZERO barriers / LDS / inter-wave coupling: waves
// free-run, slice k+1 loads pipeline under slice k MFMAs, and
// __launch_bounds__(256,3) gives 12 waves/CU of TLP.
__global__ __launch_bounds__(256, 3) void k_gru_mfma(
    const u16* __restrict__ X, const u16* __restrict__ Wih,
    const u16* __restrict__ Whh, const float* __restrict__ bif,
    const float* __restrict__ bhf, void* __restrict__ out,
    const int* __restrict__ flag, int N)
{
    int isb = flag[0];
    int tid = threadIdx.x;
    int wave = tid >> 6, lane = tid & 63;
    int qm = lane >> 4, qr = lane & 15;
    int row0 = (blockIdx.x * 4 + wave) * 16;

    // A fragments: 16 rows x K=256 (cols 0..127 = agg, 128..255 = h).
    bf16x8 a[8];
    {
        const u16* xbp = X + (size_t)(row0 + qr) * 256 + qm * 8;
        #pragma unroll
        for (int s = 0; s < 8; ++s) a[s] = *(const bf16x8*)(xbp + s * 32);
    }

    float h0v[8][4];                 // [slice][r], compile-time indexed
    float ss[4] = {0.f, 0.f, 0.f, 0.f};

    #pragma unroll
    for (int sl = 0; sl < 8; ++sl) {
        int col = sl * 16 + qr;
        f32x4 zz = {0.f, 0.f, 0.f, 0.f};
        f32x4 accR = zz, accZ = zz, accN = zz, accH = zz;

        {   // r gate: Wih rows [col], Whh rows [col]
            bf16x8 w[12];
            const u16* p1 = Wih + (size_t)col * 256 + qm * 8;
            #pragma unroll
            for (int s = 0; s < 8; ++s) w[s] = *(const bf16x8*)(p1 + s * 32);
            const u16* p2 = Whh + (size_t)col * 128 + qm * 8;
            #pragma unroll
            for (int s = 0; s < 4; ++s) w[8 + s] = *(const bf16x8*)(p2 + s * 32);
            #pragma unroll
            for (int s = 0; s < 8; ++s)
                accR = __builtin_amdgcn_mfma_f32_16x16x32_bf16(a[s], w[s], accR, 0, 0, 0);
            #pragma unroll
            for (int s = 0; s < 4; ++s)
                accR = __builtin_amdgcn_mfma_f32_16x16x32_bf16(a[4 + s], w[8 + s], accR, 0, 0, 0);
        }
        {   // z gate: rows [128+col]
            bf16x8 w[12];
            const u16* p1 = Wih + (size_t)(128 + col) * 256 + qm * 8;
            #pragma unroll
            for (int s = 0; s < 8; ++s) w[s] = *(const bf16x8*)(p1 + s * 32);
            const u16* p2 = Whh + (size_t)(128 + col) * 128 + qm * 8;
            #pragma unroll
            for (int s = 0; s < 4; ++s) w[8 + s] = *(const bf16x8*)(p2 + s * 32);
            #pragma unroll
            for (int s = 0; s < 8; ++s)
                accZ = __builtin_amdgcn_mfma_f32_16x16x32_bf16(a[s], w[s], accZ, 0, 0, 0);
            #pragma unroll
            for (int s = 0; s < 4; ++s)
                accZ = __builtin_amdgcn_mfma_f32_16x16x32_bf16(a[4 + s], w[8 + s], accZ, 0, 0, 0);
        }
        {   // n gate: Wih rows [256+col] -> accN; Whh rows [256+col] -> accH
            bf16x8 w[12];
            const u16* p1 = Wih + (size_t)(256 + col) * 256 + qm * 8;
            #pragma unroll
            for (int s = 0; s < 8; ++s) w[s] = *(const bf16x8*)(p1 + s * 32);
            const u16* p2 = Whh + (size_t)(256 + col) * 128 + qm * 8;
            #pragma unroll
            for (int s = 0; s < 4; ++s) w[8 + s] = *(const bf16x8*)(p2 + s * 32);
            #pragma unroll
            for (int s = 0; s < 8; ++s)
                accN = __builtin_amdgcn_mfma_f32_16x16x32_bf16(a[s], w[s], accN, 0, 0, 0);
            #pragma unroll
            for (int s = 0; s < 4; ++s)
                accH = __builtin_amdgcn_mfma_f32_16x16x32_bf16(a[4 + s], w[8 + s], accH, 0, 0, 0);
        }

        float brz = bif[col] + bhf[col];
        float bzz = bif[128 + col] + bhf[128 + col];
        float bnx = bif[256 + col];
        float bnh = bhf[256 + col];

        #pragma unroll
        for (int r = 0; r < 4; ++r) {
            float rg = sigm(accR[r] + brz);
            float z  = sigm(accZ[r] + bzz);
            float ng = tanh_fast(accN[r] + bnx + rg * (accH[r] + bnh));
            // h re-read: same X rows this wave just fetched -> L1-hot.
            float h  = bf2f(X[(size_t)(row0 + qm * 4 + r) * 256 + 128 + col]);
            float h0 = fmaxf((1.f - z) * ng + z * h, 0.f);
            h0v[sl][r] = h0;
            ss[r] += h0 * h0;
        }
    }

    // Full-row norm, in-wave: reduce over the 16 qr lanes (xor bits 0..3).
    float inv[4];
    #pragma unroll
    for (int r = 0; r < 4; ++r) {
        float s = ss[r];
        s += __shfl_xor(s, 1, 64);
        s += __shfl_xor(s, 2, 64);
        s += __shfl_xor(s, 4, 64);
        s += __shfl_xor(s, 8, 64);
        inv[r] = 1.f / fmaxf(sqrtf(s), 1e-12f);
    }

    #pragma unroll
    for (int sl = 0; sl < 8; ++sl) {
        int col = sl * 16 + qr;
        #pragma unroll
        for (int r = 0; r < 4; ++r) {
            int grow = row0 + qm * 4 + r;
            if (grow < N) {
                float v = h0v[sl][r] * inv[r];
                if (isb) ((u16*)out)[(size_t)grow * 128 + col] = f2bf(v);
                else     ((float*)out)[(size_t)grow * 128 + col] = v;
            }
        }
    }
}

extern "C" void kernel_launch(void* const* d_in, const int* in_sizes, int n_in,
                              void* d_out, int out_size, void* d_ws, size_t ws_size,
                              hipStream_t stream) {
    const void* ent     = d_in[0];
    const void* bias    = d_in[2];
    const void* onorm   = d_in[3];
    const void* W       = d_in[4];
    const void* w_ih    = d_in[5];
    const void* w_hh    = d_in[6];
    const void* b_ih    = d_in[7];
    const void* b_hh    = d_in[8];
    const void* node_id = d_in[9];
    const int*  esrc    = (const int*)d_in[10];
    const int*  edst    = (const int*)d_in[11];

    int N = in_sizes[2] / D;     // 100000
    int E = in_sizes[10];        // 1600000
    int NpadX = ((N + 127) / 128) * 128;   // X padded past the 64-row block grid

    char* ws = (char*)d_ws;
    size_t o = 0;
    int*   flag = (int*)(ws + o);   o += 64;
    u16*   WTb  = (u16*)(ws + o);   o += 16384u * 2;
    u16*   Wihb = (u16*)(ws + o);   o += 98304u * 2;
    u16*   Whhb = (u16*)(ws + o);   o += 49152u * 2;
    float* bif  = (float*)(ws + o); o += 2048;
    float* bhf  = (float*)(ws + o); o += 2048;
    u16*   X    = (u16*)(ws + o);   o += (size_t)NpadX * 256 * 2;
    u16*   hW   = (u16*)(ws + o);   o += (size_t)N * D * 2;
    int*   cnt  = (int*)(ws + o);   o += (size_t)N * 4;
    int*   rowstart = (int*)(ws + o); o += ((size_t)N + 16) * 4;
    int*   part = (int*)(ws + o);   o += 4096;
    int*   sorted_src = (int*)(ws + o); o += (size_t)E * 4;
    int*   cursor = cnt;

    int nb = (N + 1023) / 1024;

    k_detect<<<1, 64, 0, stream>>>(ent, node_id, flag);
    k_prep<<<643, 256, 0, stream>>>(w_ih, w_hh, b_ih, b_hh, W, flag,
                                    WTb, Wihb, Whhb, bif, bhf);
    k_zero<<<(N + 255) / 256, 256, 0, stream>>>(cnt, N);
    k_gmm_mfma<<<(N + 63) / 64, 256, 0, stream>>>(ent, node_id, WTb, hW, flag, N);
    k_hist<<<(E + 255) / 256, 256, 0, stream>>>(edst, cnt, E);
    k_scan1<<<nb, 256, 0, stream>>>(cnt, rowstart, part, N);
    k_scan2<<<1, 128, 0, stream>>>(part, rowstart, nb, N);
    k_scan3<<<(N + 255) / 256, 256, 0, stream>>>(rowstart, part, cursor, N);
    k_fill<<<(E + 255) / 256, 256, 0, stream>>>(esrc, edst, cursor, sorted_src, E);
    k_seg<<<(N + 3) / 4, 256, 0, stream>>>(hW, rowstart, sorted_src, onorm, bias, X, flag, N);
    // 4 waves/block x 16 rows/wave = 64 rows/block
    k_gru_mfma<<<(N + 63) / 64, 256, 0, stream>>>(X, Wihb, Whhb, bif, bhf, d_out, flag, N);
}

// Round 5
// 740.099 us; speedup vs baseline: 1.0066x; 1.0066x over previous
//
#include <hip/hip_runtime.h>
#include <hip/hip_bf16.h>

#define D 128

typedef unsigned short u16;
typedef unsigned int   u32;
typedef unsigned long long u64;
typedef short bf16x8 __attribute__((ext_vector_type(8)));
typedef float f32x4  __attribute__((ext_vector_type(4)));

__device__ __forceinline__ float bf2f(u16 u) {
    union { u32 i; float f; } v; v.i = ((u32)u) << 16; return v.f;
}
__device__ __forceinline__ float bflo(u32 p) {
    union { u32 i; float f; } v; v.i = p << 16; return v.f;
}
__device__ __forceinline__ float bfhi(u32 p) {
    union { u32 i; float f; } v; v.i = p & 0xffff0000u; return v.f;
}
__device__ __forceinline__ u16 f2bf(float f) {
    union { float f; u32 i; } v; v.f = f;
    return (u16)((v.i + 0x7fffu + ((v.i >> 16) & 1u)) >> 16);
}
__device__ __forceinline__ float ldf(const void* p, long i, int isb) {
    return isb ? bf2f(((const u16*)p)[i]) : ((const float*)p)[i];
}

__device__ __forceinline__ float sigm(float x) { return 1.0f / (1.0f + __expf(-x)); }
__device__ __forceinline__ float tanh_fast(float x) {
    float a = fabsf(x);
    float t = __expf(-2.0f * a);
    float r = (1.0f - t) / (1.0f + t);
    return copysignf(r, x);
}

__global__ void DRlocal_net_79173427135059_kernel() {}

// K-1: runtime dtype detection. flag[0]=inputs-are-bf16, flag[1]=node_id-is-int64.
__global__ __launch_bounds__(64) void k_detect(const void* ent, const void* nid, int* flag) {
    int lane = threadIdx.x;
    float a = fabsf(bf2f(((const u16*)ent)[lane]));
    bool sane = (a >= 9.765625e-4f && a <= 64.0f);
    u64 m = __ballot(sane);
    u32 w = ((const u32*)nid)[lane];
    bool oddzero = ((lane & 1) == 0) || (w == 0u);
    u64 m2 = __ballot(oddzero);
    if (lane == 0) {
        flag[0] = (__popcll(m) >= 48) ? 1 : 0;
        flag[1] = (m2 == ~0ull) ? 1 : 0;
    }
}

// K0: WTb[j][k] = bf16(W[k][j]); GRU weights -> bf16 as-is; biases -> f32.
__global__ __launch_bounds__(256) void k_prep(
    const void* __restrict__ w_ih, const void* __restrict__ w_hh,
    const void* __restrict__ b_ih, const void* __restrict__ b_hh,
    const void* __restrict__ W, const int* __restrict__ flag,
    u16* __restrict__ WTb, u16* __restrict__ Wihb, u16* __restrict__ Whhb,
    float* __restrict__ bif, float* __restrict__ bhf)
{
    int isb = flag[0];
    int t = blockIdx.x * 256 + threadIdx.x;
    if (t < 16384) {
        int k = t >> 7, j = t & 127;
        u16 v = isb ? ((const u16*)W)[t] : f2bf(((const float*)W)[t]);
        WTb[j * 128 + k] = v;
        return;
    }
    int u = t - 16384;
    if (u < 98304) { Wihb[u] = isb ? ((const u16*)w_ih)[u] : f2bf(((const float*)w_ih)[u]); return; }
    int v = u - 98304;
    if (v < 49152) { Whhb[v] = isb ? ((const u16*)w_hh)[v] : f2bf(((const float*)w_hh)[v]); return; }
    int b = v - 49152;
    if (b < 384) { bif[b] = ldf(b_ih, b, isb); return; }
    int c = b - 384;
    if (c < 384) { bhf[c] = ldf(b_hh, c, isb); return; }
}

__global__ __launch_bounds__(256) void k_zero(int* __restrict__ cnt, int n) {
    int t = blockIdx.x * 256 + threadIdx.x;
    if (t < n) cnt[t] = 0;
}

// K1: hW = gather(ent, node_id) @ W via MFMA. 64 nodes/block, wave = one 16-row m-tile.
// A-frags gathered straight to registers; B = WTb rows (L1-resident).
__global__ __launch_bounds__(256) void k_gmm_mfma(
    const void* __restrict__ ent, const void* __restrict__ node_id,
    const u16* __restrict__ WTb, u16* __restrict__ hW,
    const int* __restrict__ flag, int N)
{
    int isb = flag[0], i64 = flag[1];
    int tid = threadIdx.x;
    int wave = tid >> 6, lane = tid & 63;
    int qm = lane >> 4, qr = lane & 15;
    int row0 = blockIdx.x * 64 + wave * 16;

    int rowA = row0 + qr; if (rowA >= N) rowA = N - 1;
    long nid = i64 ? (long)((const long long*)node_id)[rowA]
                   : (long)((const int*)node_id)[rowA];

    // A[m=qr][k = s*32 + qm*8 + j]
    bf16x8 a[4];
    if (isb) {
        const u16* ep = (const u16*)ent + nid * 128 + qm * 8;
        #pragma unroll
        for (int s = 0; s < 4; ++s) a[s] = *(const bf16x8*)(ep + s * 32);
    } else {
        const float* ep = (const float*)ent + nid * 128 + qm * 8;
        #pragma unroll
        for (int s = 0; s < 4; ++s) {
            float4 f0 = *(const float4*)(ep + s * 32);
            float4 f1 = *(const float4*)(ep + s * 32 + 4);
            bf16x8 t;
            t[0] = (short)f2bf(f0.x); t[1] = (short)f2bf(f0.y);
            t[2] = (short)f2bf(f0.z); t[3] = (short)f2bf(f0.w);
            t[4] = (short)f2bf(f1.x); t[5] = (short)f2bf(f1.y);
            t[6] = (short)f2bf(f1.z); t[7] = (short)f2bf(f1.w);
            a[s] = t;
        }
    }

    int r0 = row0 + qm * 4;
    #pragma unroll
    for (int f = 0; f < 8; ++f) {
        f32x4 acc = {0.f, 0.f, 0.f, 0.f};
        const u16* wp = WTb + (size_t)(f * 16 + qr) * 128 + qm * 8;
        #pragma unroll
        for (int s = 0; s < 4; ++s) {
            bf16x8 b = *(const bf16x8*)(wp + s * 32);
            acc = __builtin_amdgcn_mfma_f32_16x16x32_bf16(a[s], b, acc, 0, 0, 0);
        }
        int col = f * 16 + qr;
        #pragma unroll
        for (int r = 0; r < 4; ++r) {
            int row = r0 + r;
            if (row < N) hW[(size_t)row * 128 + col] = f2bf(acc[r]);
        }
    }
}

// ---- CSR build ----
__global__ __launch_bounds__(256) void k_hist(
    const int* __restrict__ edst, int* __restrict__ cnt, int E)
{
    int e = blockIdx.x * 256 + threadIdx.x;
    if (e < E) atomicAdd(&cnt[edst[e]], 1);
}

__global__ __launch_bounds__(256) void k_scan1(
    const int* __restrict__ cnt, int* __restrict__ rowstart,
    int* __restrict__ part, int N)
{
    __shared__ int ssum[256];
    int b = blockIdx.x, t = threadIdx.x;
    int base = b * 1024 + t * 4;
    int v[4]; int s = 0;
    #pragma unroll
    for (int i = 0; i < 4; ++i) {
        int idx = base + i;
        v[i] = (idx < N) ? cnt[idx] : 0;
        s += v[i];
    }
    ssum[t] = s;
    __syncthreads();
    #pragma unroll
    for (int off = 1; off < 256; off <<= 1) {
        int x = (t >= off) ? ssum[t - off] : 0;
        __syncthreads();
        ssum[t] += x;
        __syncthreads();
    }
    int run = ssum[t] - s;
    #pragma unroll
    for (int i = 0; i < 4; ++i) {
        int idx = base + i;
        if (idx < N) rowstart[idx] = run;
        run += v[i];
    }
    if (t == 255) part[b] = ssum[255];
}

// Parallel 128-lane scan over the nb block partials.
__global__ __launch_bounds__(128) void k_scan2(
    int* __restrict__ part, int* __restrict__ rowstart, int nb, int N)
{
    __shared__ int sh[128];
    int t = threadIdx.x;
    int run = 0;
    for (int base = 0; base < nb; base += 128) {
        int i = base + t;
        int v = (i < nb) ? part[i] : 0;
        sh[t] = v;
        __syncthreads();
        #pragma unroll
        for (int off = 1; off < 128; off <<= 1) {
            int x = (t >= off) ? sh[t - off] : 0;
            __syncthreads();
            sh[t] += x;
            __syncthreads();
        }
        int incl = sh[t];
        if (i < nb) part[i] = run + incl - v;   // exclusive prefix
        int tot = sh[127];
        __syncthreads();
        run += tot;
    }
    if (t == 0) rowstart[N] = run;
}

__global__ __launch_bounds__(256) void k_scan3(
    int* __restrict__ rowstart, const int* __restrict__ part,
    int* __restrict__ cursor, int N)
{
    int t = blockIdx.x * 256 + threadIdx.x;
    if (t < N) {
        int r = rowstart[t] + part[t >> 10];
        rowstart[t] = r;
        cursor[t] = r;
    }
}

__global__ __launch_bounds__(256) void k_fill(
    const int* __restrict__ esrc, const int* __restrict__ edst,
    int* __restrict__ cursor, int* __restrict__ sorted_src, int E)
{
    int e = blockIdx.x * 256 + threadIdx.x;
    if (e < E) {
        int d = edst[e];
        int pos = atomicAdd(&cursor[d], 1);
        sorted_src[pos] = esrc[e];
    }
}

// K3: segment sum -> X[:,0:128] = bf16(agg*out_norm); also X[:,128:256] = e_r_bias.
// 8-deep gather unroll for MLP on the 410 MB edge gather.
__global__ __launch_bounds__(256) void k_seg(
    const u16* __restrict__ hW, const int* __restrict__ rowstart,
    const int* __restrict__ sorted_src, const void* __restrict__ onorm,
    const void* __restrict__ bias, u16* __restrict__ X,
    const int* __restrict__ flag, int N)
{
    int isb = flag[0];
    int tid = threadIdx.x;
    int node = blockIdx.x * 4 + (tid >> 6);
    int lane = tid & 63;
    if (node >= N) return;
    int beg = rowstart[node], end = rowstart[node + 1];
    const u32* hw2 = (const u32*)hW;
    float a0 = 0.f, a1 = 0.f;
    int e = beg;
    for (; e + 8 <= end; e += 8) {
        int sI[8]; u32 vI[8];
        #pragma unroll
        for (int i = 0; i < 8; ++i) sI[i] = sorted_src[e + i];
        #pragma unroll
        for (int i = 0; i < 8; ++i) vI[i] = hw2[(size_t)sI[i] * 64 + lane];
        #pragma unroll
        for (int i = 0; i < 8; ++i) { a0 += bflo(vI[i]); a1 += bfhi(vI[i]); }
    }
    for (; e + 4 <= end; e += 4) {
        int s0 = sorted_src[e], s1 = sorted_src[e + 1];
        int s2 = sorted_src[e + 2], s3 = sorted_src[e + 3];
        u32 v0 = hw2[(size_t)s0 * 64 + lane];
        u32 v1 = hw2[(size_t)s1 * 64 + lane];
        u32 v2 = hw2[(size_t)s2 * 64 + lane];
        u32 v3 = hw2[(size_t)s3 * 64 + lane];
        a0 += bflo(v0) + bflo(v1) + bflo(v2) + bflo(v3);
        a1 += bfhi(v0) + bfhi(v1) + bfhi(v2) + bfhi(v3);
    }
    for (; e < end; ++e) {
        u32 v = hw2[(size_t)sorted_src[e] * 64 + lane];
        a0 += bflo(v); a1 += bfhi(v);
    }
    float on = ldf(onorm, node, isb);
    u32 p = ((u32)f2bf(a1 * on) << 16) | (u32)f2bf(a0 * on);
    ((u32*)X)[(size_t)node * 128 + lane] = p;
    // bias half
    u32 pb;
    if (isb) pb = ((const u32*)bias)[(size_t)node * 64 + lane];
    else {
        const float* bp = (const float*)bias + (size_t)node * 128 + lane * 2;
        pb = ((u32)f2bf(bp[1]) << 16) | (u32)f2bf(bp[0]);
    }
    ((u32*)X)[(size_t)node * 128 + 64 + lane] = pb;
}

// K4 v5: wave-independent MFMA GRU with LDS h0 staging (register diet).
// One wave = 16 rows x all 128 cols, runtime loop over 8 col-slices
// (#pragma unroll 1 -- no register arrays indexed by slice, so no unroll
// blow-up; R4's h0v[8][4]+a[8] register demand forced an 84-reg spill).
// h0 goes to a padded per-wave LDS tile; norm = in-lane slice accumulation
// + 16-lane shfl_xor; linv passes through LDS within the wave. Zero
// __syncthreads. Final store reads LDS back in a coalesced f32x4 mapping.
__global__ __launch_bounds__(256, 3) void k_gru_mfma(
    const u16* __restrict__ X, const u16* __restrict__ Wih,
    const u16* __restrict__ Whh, const float* __restrict__ bif,
    const float* __restrict__ bhf, void* __restrict__ out,
    const int* __restrict__ flag, int N)
{
    __shared__ float h0s[4][16][132];   // [wave][row][col], +4 pad
    __shared__ float linv[4][16];
    int isb = flag[0];
    int tid = threadIdx.x;
    int wave = tid >> 6, lane = tid & 63;
    int qm = lane >> 4, qr = lane & 15;
    int row0 = (blockIdx.x * 4 + wave) * 16;

    // A fragments: 16 rows x K=256 (cols 0..127 = agg, 128..255 = h). Live
    // across the whole kernel: 32 VGPRs.
    bf16x8 a[8];
    {
        const u16* xbp = X + (size_t)(row0 + qr) * 256 + qm * 8;
        #pragma unroll
        for (int s = 0; s < 8; ++s) a[s] = *(const bf16x8*)(xbp + s * 32);
    }

    float ss0 = 0.f, ss1 = 0.f, ss2 = 0.f, ss3 = 0.f;

    #pragma unroll 1
    for (int sl = 0; sl < 8; ++sl) {
        int col = sl * 16 + qr;
        f32x4 zz = {0.f, 0.f, 0.f, 0.f};
        f32x4 accR = zz, accZ = zz, accN = zz, accH = zz;

        const u16* pR1 = Wih + (size_t)col * 256 + qm * 8;
        const u16* pZ1 = Wih + (size_t)(128 + col) * 256 + qm * 8;
        const u16* pN1 = Wih + (size_t)(256 + col) * 256 + qm * 8;
        const u16* pR2 = Whh + (size_t)col * 128 + qm * 8;
        const u16* pZ2 = Whh + (size_t)(128 + col) * 128 + qm * 8;
        const u16* pN2 = Whh + (size_t)(256 + col) * 128 + qm * 8;

        {   // r gate
            bf16x8 w[12];
            #pragma unroll
            for (int s = 0; s < 8; ++s) w[s] = *(const bf16x8*)(pR1 + s * 32);
            #pragma unroll
            for (int s = 0; s < 4; ++s) w[8 + s] = *(const bf16x8*)(pR2 + s * 32);
            #pragma unroll
            for (int s = 0; s < 8; ++s)
                accR = __builtin_amdgcn_mfma_f32_16x16x32_bf16(a[s], w[s], accR, 0, 0, 0);
            #pragma unroll
            for (int s = 0; s < 4; ++s)
                accR = __builtin_amdgcn_mfma_f32_16x16x32_bf16(a[4 + s], w[8 + s], accR, 0, 0, 0);
        }
        {   // z gate
            bf16x8 w[12];
            #pragma unroll
            for (int s = 0; s < 8; ++s) w[s] = *(const bf16x8*)(pZ1 + s * 32);
            #pragma unroll
            for (int s = 0; s < 4; ++s) w[8 + s] = *(const bf16x8*)(pZ2 + s * 32);
            #pragma unroll
            for (int s = 0; s < 8; ++s)
                accZ = __builtin_amdgcn_mfma_f32_16x16x32_bf16(a[s], w[s], accZ, 0, 0, 0);
            #pragma unroll
            for (int s = 0; s < 4; ++s)
                accZ = __builtin_amdgcn_mfma_f32_16x16x32_bf16(a[4 + s], w[8 + s], accZ, 0, 0, 0);
        }
        {   // n gate: Wih -> accN; Whh -> accH
            bf16x8 w[12];
            #pragma unroll
            for (int s = 0; s < 8; ++s) w[s] = *(const bf16x8*)(pN1 + s * 32);
            #pragma unroll
            for (int s = 0; s < 4; ++s) w[8 + s] = *(const bf16x8*)(pN2 + s * 32);
            #pragma unroll
            for (int s = 0; s < 8; ++s)
                accN = __builtin_amdgcn_mfma_f32_16x16x32_bf16(a[s], w[s], accN, 0, 0, 0);
            #pragma unroll
            for (int s = 0; s < 4; ++s)
                accH = __builtin_amdgcn_mfma_f32_16x16x32_bf16(a[4 + s], w[8 + s], accH, 0, 0, 0);
        }

        float brz = bif[col] + bhf[col];
        float bzz = bif[128 + col] + bhf[128 + col];
        float bnx = bif[256 + col];
        float bnh = bhf[256 + col];

        #pragma unroll
        for (int r = 0; r < 4; ++r) {
            float rg = sigm(accR[r] + brz);
            float z  = sigm(accZ[r] + bzz);
            float ng = tanh_fast(accN[r] + bnx + rg * (accH[r] + bnh));
            // h re-read: same X rows this wave just fetched -> L1-hot.
            float h  = bf2f(X[(size_t)(row0 + qm * 4 + r) * 256 + 128 + col]);
            float h0 = fmaxf((1.f - z) * ng + z * h, 0.f);
            h0s[wave][qm * 4 + r][col] = h0;
            float q = h0 * h0;
            if (r == 0) ss0 += q; else if (r == 1) ss1 += q;
            else if (r == 2) ss2 += q; else ss3 += q;
        }
    }

    // Row norm: reduce each ss over the 16 qr lanes (xor bits 0..3).
    {
        float sv[4] = {ss0, ss1, ss2, ss3};
        #pragma unroll
        for (int r = 0; r < 4; ++r) {
            float s = sv[r];
            s += __shfl_xor(s, 1, 64);
            s += __shfl_xor(s, 2, 64);
            s += __shfl_xor(s, 4, 64);
            s += __shfl_xor(s, 8, 64);
            sv[r] = s;
        }
        if (qr == 0) {
            #pragma unroll
            for (int r = 0; r < 4; ++r)
                linv[wave][qm * 4 + r] = 1.f / fmaxf(sqrtf(sv[r]), 1e-12f);
        }
    }
    // Intra-wave LDS dependency only: lanes read other lanes' h0s/linv, but
    // wave64 executes in lockstep and the compiler orders LDS ops with
    // lgkmcnt -- no barrier needed.

    // Coalesced store: 2 rows x 128 cols per iter, f32x4 per lane.
    #pragma unroll 1
    for (int it = 0; it < 8; ++it) {
        int row  = it * 2 + (lane >> 5);
        int c4   = (lane & 31) * 4;
        int grow = row0 + row;
        if (grow < N) {
            float iv = linv[wave][row];
            const float* hp = &h0s[wave][row][c4];
            float v0 = hp[0] * iv, v1 = hp[1] * iv, v2 = hp[2] * iv, v3 = hp[3] * iv;
            if (isb) {
                u64 pk = (u64)f2bf(v0) | ((u64)f2bf(v1) << 16)
                       | ((u64)f2bf(v2) << 32) | ((u64)f2bf(v3) << 48);
                *(u64*)((u16*)out + (size_t)grow * 128 + c4) = pk;
            } else {
                float4 o = {v0, v1, v2, v3};
                *(float4*)((float*)out + (size_t)grow * 128 + c4) = o;
            }
        }
    }
}

extern "C" void kernel_launch(void* const* d_in, const int* in_sizes, int n_in,
                              void* d_out, int out_size, void* d_ws, size_t ws_size,
                              hipStream_t stream) {
    const void* ent     = d_in[0];
    const void* bias    = d_in[2];
    const void* onorm   = d_in[3];
    const void* W       = d_in[4];
    const void* w_ih    = d_in[5];
    const void* w_hh    = d_in[6];
    const void* b_ih    = d_in[7];
    const void* b_hh    = d_in[8];
    const void* node_id = d_in[9];
    const int*  esrc    = (const int*)d_in[10];
    const int*  edst    = (const int*)d_in[11];

    int N = in_sizes[2] / D;     // 100000
    int E = in_sizes[10];        // 1600000
    int NpadX = ((N + 127) / 128) * 128;   // X padded past the 64-row block grid

    char* ws = (char*)d_ws;
    size_t o = 0;
    int*   flag = (int*)(ws + o);   o += 64;
    u16*   WTb  = (u16*)(ws + o);   o += 16384u * 2;
    u16*   Wihb = (u16*)(ws + o);   o += 98304u * 2;
    u16*   Whhb = (u16*)(ws + o);   o += 49152u * 2;
    float* bif  = (float*)(ws + o); o += 2048;
    float* bhf  = (float*)(ws + o); o += 2048;
    u16*   X    = (u16*)(ws + o);   o += (size_t)NpadX * 256 * 2;
    u16*   hW   = (u16*)(ws + o);   o += (size_t)N * D * 2;
    int*   cnt  = (int*)(ws + o);   o += (size_t)N * 4;
    int*   rowstart = (int*)(ws + o); o += ((size_t)N + 16) * 4;
    int*   part = (int*)(ws + o);   o += 4096;
    int*   sorted_src = (int*)(ws + o); o += (size_t)E * 4;
    int*   cursor = cnt;

    int nb = (N + 1023) / 1024;

    k_detect<<<1, 64, 0, stream>>>(ent, node_id, flag);
    k_prep<<<643, 256, 0, stream>>>(w_ih, w_hh, b_ih, b_hh, W, flag,
                                    WTb, Wihb, Whhb, bif, bhf);
    k_zero<<<(N + 255) / 256, 256, 0, stream>>>(cnt, N);
    k_gmm_mfma<<<(N + 63) / 64, 256, 0, stream>>>(ent, node_id, WTb, hW, flag, N);
    k_hist<<<(E + 255) / 256, 256, 0, stream>>>(edst, cnt, E);
    k_scan1<<<nb, 256, 0, stream>>>(cnt, rowstart, part, N);
    k_scan2<<<1, 128, 0, stream>>>(part, rowstart, nb, N);
    k_scan3<<<(N + 255) / 256, 256, 0, stream>>>(rowstart, part, cursor, N);
    k_fill<<<(E + 255) / 256, 256, 0, stream>>>(esrc, edst, cursor, sorted_src, E);
    k_seg<<<(N + 3) / 4, 256, 0, stream>>>(hW, rowstart, sorted_src, onorm, bias, X, flag, N);
    // 4 waves/block x 16 rows/wave = 64 rows/block
    k_gru_mfma<<<(N + 63) / 64, 256, 0, stream>>>(X, Wihb, Whhb, bif, bhf, d_out, flag, N);
}

// Round 6
// 622.403 us; speedup vs baseline: 1.1969x; 1.1891x over previous
//
#include <hip/hip_runtime.h>
#include <hip/hip_bf16.h>

#define D 128

typedef unsigned short u16;
typedef unsigned int   u32;
typedef unsigned long long u64;
typedef short bf16x8 __attribute__((ext_vector_type(8)));
typedef float f32x4  __attribute__((ext_vector_type(4)));

__device__ __forceinline__ float bf2f(u16 u) {
    union { u32 i; float f; } v; v.i = ((u32)u) << 16; return v.f;
}
__device__ __forceinline__ float bflo(u32 p) {
    union { u32 i; float f; } v; v.i = p << 16; return v.f;
}
__device__ __forceinline__ float bfhi(u32 p) {
    union { u32 i; float f; } v; v.i = p & 0xffff0000u; return v.f;
}
__device__ __forceinline__ u16 f2bf(float f) {
    union { float f; u32 i; } v; v.f = f;
    return (u16)((v.i + 0x7fffu + ((v.i >> 16) & 1u)) >> 16);
}
__device__ __forceinline__ float ldf(const void* p, long i, int isb) {
    return isb ? bf2f(((const u16*)p)[i]) : ((const float*)p)[i];
}

__device__ __forceinline__ float sigm(float x) { return 1.0f / (1.0f + __expf(-x)); }
__device__ __forceinline__ float tanh_fast(float x) {
    float a = fabsf(x);
    float t = __expf(-2.0f * a);
    float r = (1.0f - t) / (1.0f + t);
    return copysignf(r, x);
}

__global__ void DRlocal_net_79173427135059_kernel() {}

// K-1: runtime dtype detection. flag[0]=inputs-are-bf16, flag[1]=node_id-is-int64.
__global__ __launch_bounds__(64) void k_detect(const void* ent, const void* nid, int* flag) {
    int lane = threadIdx.x;
    float a = fabsf(bf2f(((const u16*)ent)[lane]));
    bool sane = (a >= 9.765625e-4f && a <= 64.0f);
    u64 m = __ballot(sane);
    u32 w = ((const u32*)nid)[lane];
    bool oddzero = ((lane & 1) == 0) || (w == 0u);
    u64 m2 = __ballot(oddzero);
    if (lane == 0) {
        flag[0] = (__popcll(m) >= 48) ? 1 : 0;
        flag[1] = (m2 == ~0ull) ? 1 : 0;
    }
}

// K0: WTb[j][k] = bf16(W[k][j]); GRU weights -> bf16 as-is; biases -> f32.
__global__ __launch_bounds__(256) void k_prep(
    const void* __restrict__ w_ih, const void* __restrict__ w_hh,
    const void* __restrict__ b_ih, const void* __restrict__ b_hh,
    const void* __restrict__ W, const int* __restrict__ flag,
    u16* __restrict__ WTb, u16* __restrict__ Wihb, u16* __restrict__ Whhb,
    float* __restrict__ bif, float* __restrict__ bhf)
{
    int isb = flag[0];
    int t = blockIdx.x * 256 + threadIdx.x;
    if (t < 16384) {
        int k = t >> 7, j = t & 127;
        u16 v = isb ? ((const u16*)W)[t] : f2bf(((const float*)W)[t]);
        WTb[j * 128 + k] = v;
        return;
    }
    int u = t - 16384;
    if (u < 98304) { Wihb[u] = isb ? ((const u16*)w_ih)[u] : f2bf(((const float*)w_ih)[u]); return; }
    int v = u - 98304;
    if (v < 49152) { Whhb[v] = isb ? ((const u16*)w_hh)[v] : f2bf(((const float*)w_hh)[v]); return; }
    int b = v - 49152;
    if (b < 384) { bif[b] = ldf(b_ih, b, isb); return; }
    int c = b - 384;
    if (c < 384) { bhf[c] = ldf(b_hh, c, isb); return; }
}

__global__ __launch_bounds__(256) void k_zero(int* __restrict__ cnt, int n) {
    int t = blockIdx.x * 256 + threadIdx.x;
    if (t < n) cnt[t] = 0;
}

// K1: hW = gather(ent, node_id) @ W via MFMA. 64 nodes/block, wave = one 16-row m-tile.
__global__ __launch_bounds__(256) void k_gmm_mfma(
    const void* __restrict__ ent, const void* __restrict__ node_id,
    const u16* __restrict__ WTb, u16* __restrict__ hW,
    const int* __restrict__ flag, int N)
{
    int isb = flag[0], i64 = flag[1];
    int tid = threadIdx.x;
    int wave = tid >> 6, lane = tid & 63;
    int qm = lane >> 4, qr = lane & 15;
    int row0 = blockIdx.x * 64 + wave * 16;

    int rowA = row0 + qr; if (rowA >= N) rowA = N - 1;
    long nid = i64 ? (long)((const long long*)node_id)[rowA]
                   : (long)((const int*)node_id)[rowA];

    bf16x8 a[4];
    if (isb) {
        const u16* ep = (const u16*)ent + nid * 128 + qm * 8;
        #pragma unroll
        for (int s = 0; s < 4; ++s) a[s] = *(const bf16x8*)(ep + s * 32);
    } else {
        const float* ep = (const float*)ent + nid * 128 + qm * 8;
        #pragma unroll
        for (int s = 0; s < 4; ++s) {
            float4 f0 = *(const float4*)(ep + s * 32);
            float4 f1 = *(const float4*)(ep + s * 32 + 4);
            bf16x8 t;
            t[0] = (short)f2bf(f0.x); t[1] = (short)f2bf(f0.y);
            t[2] = (short)f2bf(f0.z); t[3] = (short)f2bf(f0.w);
            t[4] = (short)f2bf(f1.x); t[5] = (short)f2bf(f1.y);
            t[6] = (short)f2bf(f1.z); t[7] = (short)f2bf(f1.w);
            a[s] = t;
        }
    }

    int r0 = row0 + qm * 4;
    #pragma unroll
    for (int f = 0; f < 8; ++f) {
        f32x4 acc = {0.f, 0.f, 0.f, 0.f};
        const u16* wp = WTb + (size_t)(f * 16 + qr) * 128 + qm * 8;
        #pragma unroll
        for (int s = 0; s < 4; ++s) {
            bf16x8 b = *(const bf16x8*)(wp + s * 32);
            acc = __builtin_amdgcn_mfma_f32_16x16x32_bf16(a[s], b, acc, 0, 0, 0);
        }
        int col = f * 16 + qr;
        #pragma unroll
        for (int r = 0; r < 4; ++r) {
            int row = r0 + r;
            if (row < N) hW[(size_t)row * 128 + col] = f2bf(acc[r]);
        }
    }
}

// ---- CSR build ----
__global__ __launch_bounds__(256) void k_hist(
    const int* __restrict__ edst, int* __restrict__ cnt, int E)
{
    int e = blockIdx.x * 256 + threadIdx.x;
    if (e < E) atomicAdd(&cnt[edst[e]], 1);
}

__global__ __launch_bounds__(256) void k_scan1(
    const int* __restrict__ cnt, int* __restrict__ rowstart,
    int* __restrict__ part, int N)
{
    __shared__ int ssum[256];
    int b = blockIdx.x, t = threadIdx.x;
    int base = b * 1024 + t * 4;
    int v[4]; int s = 0;
    #pragma unroll
    for (int i = 0; i < 4; ++i) {
        int idx = base + i;
        v[i] = (idx < N) ? cnt[idx] : 0;
        s += v[i];
    }
    ssum[t] = s;
    __syncthreads();
    #pragma unroll
    for (int off = 1; off < 256; off <<= 1) {
        int x = (t >= off) ? ssum[t - off] : 0;
        __syncthreads();
        ssum[t] += x;
        __syncthreads();
    }
    int run = ssum[t] - s;
    #pragma unroll
    for (int i = 0; i < 4; ++i) {
        int idx = base + i;
        if (idx < N) rowstart[idx] = run;
        run += v[i];
    }
    if (t == 255) part[b] = ssum[255];
}

__global__ __launch_bounds__(128) void k_scan2(
    int* __restrict__ part, int* __restrict__ rowstart, int nb, int N)
{
    __shared__ int sh[128];
    int t = threadIdx.x;
    int run = 0;
    for (int base = 0; base < nb; base += 128) {
        int i = base + t;
        int v = (i < nb) ? part[i] : 0;
        sh[t] = v;
        __syncthreads();
        #pragma unroll
        for (int off = 1; off < 128; off <<= 1) {
            int x = (t >= off) ? sh[t - off] : 0;
            __syncthreads();
            sh[t] += x;
            __syncthreads();
        }
        int incl = sh[t];
        if (i < nb) part[i] = run + incl - v;   // exclusive prefix
        int tot = sh[127];
        __syncthreads();
        run += tot;
    }
    if (t == 0) rowstart[N] = run;
}

__global__ __launch_bounds__(256) void k_scan3(
    int* __restrict__ rowstart, const int* __restrict__ part,
    int* __restrict__ cursor, int N)
{
    int t = blockIdx.x * 256 + threadIdx.x;
    if (t < N) {
        int r = rowstart[t] + part[t >> 10];
        rowstart[t] = r;
        cursor[t] = r;
    }
}

__global__ __launch_bounds__(256) void k_fill(
    const int* __restrict__ esrc, const int* __restrict__ edst,
    int* __restrict__ cursor, int* __restrict__ sorted_src, int E)
{
    int e = blockIdx.x * 256 + threadIdx.x;
    if (e < E) {
        int d = edst[e];
        int pos = atomicAdd(&cursor[d], 1);
        sorted_src[pos] = esrc[e];
    }
}

// K3: segment sum -> X[:,0:128] = bf16(agg*out_norm); also X[:,128:256] = e_r_bias.
__global__ __launch_bounds__(256) void k_seg(
    const u16* __restrict__ hW, const int* __restrict__ rowstart,
    const int* __restrict__ sorted_src, const void* __restrict__ onorm,
    const void* __restrict__ bias, u16* __restrict__ X,
    const int* __restrict__ flag, int N)
{
    int isb = flag[0];
    int tid = threadIdx.x;
    int node = blockIdx.x * 4 + (tid >> 6);
    int lane = tid & 63;
    if (node >= N) return;
    int beg = rowstart[node], end = rowstart[node + 1];
    const u32* hw2 = (const u32*)hW;
    float a0 = 0.f, a1 = 0.f;
    int e = beg;
    for (; e + 8 <= end; e += 8) {
        int sI[8]; u32 vI[8];
        #pragma unroll
        for (int i = 0; i < 8; ++i) sI[i] = sorted_src[e + i];
        #pragma unroll
        for (int i = 0; i < 8; ++i) vI[i] = hw2[(size_t)sI[i] * 64 + lane];
        #pragma unroll
        for (int i = 0; i < 8; ++i) { a0 += bflo(vI[i]); a1 += bfhi(vI[i]); }
    }
    for (; e + 4 <= end; e += 4) {
        int s0 = sorted_src[e], s1 = sorted_src[e + 1];
        int s2 = sorted_src[e + 2], s3 = sorted_src[e + 3];
        u32 v0 = hw2[(size_t)s0 * 64 + lane];
        u32 v1 = hw2[(size_t)s1 * 64 + lane];
        u32 v2 = hw2[(size_t)s2 * 64 + lane];
        u32 v3 = hw2[(size_t)s3 * 64 + lane];
        a0 += bflo(v0) + bflo(v1) + bflo(v2) + bflo(v3);
        a1 += bfhi(v0) + bfhi(v1) + bfhi(v2) + bfhi(v3);
    }
    for (; e < end; ++e) {
        u32 v = hw2[(size_t)sorted_src[e] * 64 + lane];
        a0 += bflo(v); a1 += bfhi(v);
    }
    float on = ldf(onorm, node, isb);
    u32 p = ((u32)f2bf(a1 * on) << 16) | (u32)f2bf(a0 * on);
    ((u32*)X)[(size_t)node * 128 + lane] = p;
    u32 pb;
    if (isb) pb = ((const u32*)bias)[(size_t)node * 64 + lane];
    else {
        const float* bp = (const float*)bias + (size_t)node * 128 + lane * 2;
        pb = ((u32)f2bf(bp[1]) << 16) | (u32)f2bf(bp[0]);
    }
    ((u32*)X)[(size_t)node * 128 + 64 + lane] = pb;
}

// K4 v6, pass 1: LDS-weight-resident MFMA GRU, column-split.
// Grid = 2 col-groups x (NpadX/256) row-chunks. Block = 512 thr (8 waves),
// stages its 64-output-col weight slice (147456 B) into LDS ONCE, XOR-swizzled
// (L ^ ((c&7)<<4)) to kill the 512B-stride bank conflict. Each wave: 32 rows
// x 64 cols, B-frags from LDS (short-latency ds_read_b128, 2 MFMAs per frag).
// Writes UNNORMALIZED h0 to out + 64-col sumsq partials; k_norm finishes.
__global__ __launch_bounds__(512, 2) void k_gru_mfma(
    const u16* __restrict__ X, const u16* __restrict__ Wih,
    const u16* __restrict__ Whh, const float* __restrict__ bif,
    const float* __restrict__ bhf, void* __restrict__ out,
    float* __restrict__ ssb,
    const int* __restrict__ flag, int N, int NpadX)
{
    __shared__ alignas(16) char smem[147456];   // [3][64][256]ih + [3][64][128]hh
    int isb = flag[0];
    int tid = threadIdx.x;
    int wave = tid >> 6, lane = tid & 63;
    int qm = lane >> 4, qr = lane & 15;
    int g = blockIdx.x & 1;                 // column group: cols [g*64, g*64+64)
    int chunk = blockIdx.x >> 1;
    int g64 = g * 64;

    // ---- stage weights (linear global -> swizzled LDS) ----
    for (int t = tid; t < 6144; t += 512) {     // Wih region: 98304 B
        int L = t * 16;
        int kb = L & 511;
        int c  = (L >> 9) & 63;
        int gi = L >> 15;
        int src = (gi * 128 + g64 + c) * 512 + kb;
        int dst = L ^ ((c & 7) << 4);
        *(bf16x8*)(smem + dst) = *(const bf16x8*)((const char*)Wih + src);
    }
    for (int t = tid; t < 3072; t += 512) {     // Whh region: 49152 B @ 98304
        int L = t * 16;
        int kb = L & 255;
        int c  = (L >> 8) & 63;
        int gi = L >> 14;
        int src = (gi * 128 + g64 + c) * 256 + kb;
        int dst = 98304 + (L ^ ((c & 7) << 4));
        *(bf16x8*)(smem + dst) = *(const bf16x8*)((const char*)Whh + src);
    }
    __syncthreads();

    int rbase = chunk * 256 + wave * 32;

    // A fragments for 2 m-tiles (32 rows), loaded once, reused by 4 slices.
    bf16x8 aA[8], aB[8];
    {
        const u16* x0 = X + (size_t)(rbase + qr) * 256 + qm * 8;
        #pragma unroll
        for (int s = 0; s < 8; ++s) aA[s] = *(const bf16x8*)(x0 + s * 32);
        const u16* x1 = x0 + 16 * 256;
        #pragma unroll
        for (int s = 0; s < 8; ++s) aB[s] = *(const bf16x8*)(x1 + s * 32);
    }

    float ss[8] = {0.f, 0.f, 0.f, 0.f, 0.f, 0.f, 0.f, 0.f};

    #pragma unroll 1
    for (int sl = 0; sl < 4; ++sl) {
        int colIdx = sl * 16 + qr;          // 0..63 within group
        int colg = g64 + colIdx;            // global out col
        int sw = (qr & 7) << 4;
        int cbI = colIdx * 512 + qm * 16;   // Wih row base (bytes)
        int cbH = colIdx * 256 + qm * 16;   // Whh row base (bytes)

        f32x4 zz = {0.f, 0.f, 0.f, 0.f};
        f32x4 aR0 = zz, aR1 = zz, aZ0 = zz, aZ1 = zz;
        f32x4 aN0 = zz, aN1 = zz, aH0 = zz, aH1 = zz;

        {   // r gate
            bf16x8 w[12];
            #pragma unroll
            for (int s = 0; s < 8; ++s)
                w[s] = *(const bf16x8*)(smem + ((cbI + s * 64) ^ sw));
            #pragma unroll
            for (int s = 0; s < 4; ++s)
                w[8 + s] = *(const bf16x8*)(smem + 98304 + ((cbH + s * 64) ^ sw));
            #pragma unroll
            for (int s = 0; s < 8; ++s) {
                aR0 = __builtin_amdgcn_mfma_f32_16x16x32_bf16(aA[s], w[s], aR0, 0, 0, 0);
                aR1 = __builtin_amdgcn_mfma_f32_16x16x32_bf16(aB[s], w[s], aR1, 0, 0, 0);
            }
            #pragma unroll
            for (int s = 0; s < 4; ++s) {
                aR0 = __builtin_amdgcn_mfma_f32_16x16x32_bf16(aA[4 + s], w[8 + s], aR0, 0, 0, 0);
                aR1 = __builtin_amdgcn_mfma_f32_16x16x32_bf16(aB[4 + s], w[8 + s], aR1, 0, 0, 0);
            }
        }
        {   // z gate (+32768 ih, +16384 hh)
            bf16x8 w[12];
            #pragma unroll
            for (int s = 0; s < 8; ++s)
                w[s] = *(const bf16x8*)(smem + 32768 + ((cbI + s * 64) ^ sw));
            #pragma unroll
            for (int s = 0; s < 4; ++s)
                w[8 + s] = *(const bf16x8*)(smem + 98304 + 16384 + ((cbH + s * 64) ^ sw));
            #pragma unroll
            for (int s = 0; s < 8; ++s) {
                aZ0 = __builtin_amdgcn_mfma_f32_16x16x32_bf16(aA[s], w[s], aZ0, 0, 0, 0);
                aZ1 = __builtin_amdgcn_mfma_f32_16x16x32_bf16(aB[s], w[s], aZ1, 0, 0, 0);
            }
            #pragma unroll
            for (int s = 0; s < 4; ++s) {
                aZ0 = __builtin_amdgcn_mfma_f32_16x16x32_bf16(aA[4 + s], w[8 + s], aZ0, 0, 0, 0);
                aZ1 = __builtin_amdgcn_mfma_f32_16x16x32_bf16(aB[4 + s], w[8 + s], aZ1, 0, 0, 0);
            }
        }
        {   // n gate: ih -> aN, hh -> aH
            bf16x8 w[12];
            #pragma unroll
            for (int s = 0; s < 8; ++s)
                w[s] = *(const bf16x8*)(smem + 65536 + ((cbI + s * 64) ^ sw));
            #pragma unroll
            for (int s = 0; s < 4; ++s)
                w[8 + s] = *(const bf16x8*)(smem + 98304 + 32768 + ((cbH + s * 64) ^ sw));
            #pragma unroll
            for (int s = 0; s < 8; ++s) {
                aN0 = __builtin_amdgcn_mfma_f32_16x16x32_bf16(aA[s], w[s], aN0, 0, 0, 0);
                aN1 = __builtin_amdgcn_mfma_f32_16x16x32_bf16(aB[s], w[s], aN1, 0, 0, 0);
            }
            #pragma unroll
            for (int s = 0; s < 4; ++s) {
                aH0 = __builtin_amdgcn_mfma_f32_16x16x32_bf16(aA[4 + s], w[8 + s], aH0, 0, 0, 0);
                aH1 = __builtin_amdgcn_mfma_f32_16x16x32_bf16(aB[4 + s], w[8 + s], aH1, 0, 0, 0);
            }
        }

        float brz = bif[colg] + bhf[colg];
        float bzz = bif[128 + colg] + bhf[128 + colg];
        float bnx = bif[256 + colg];
        float bnh = bhf[256 + colg];

        #pragma unroll
        for (int ms = 0; ms < 2; ++ms) {
            #pragma unroll
            for (int r = 0; r < 4; ++r) {
                float vR = ms ? aR1[r] : aR0[r];
                float vZ = ms ? aZ1[r] : aZ0[r];
                float vN = ms ? aN1[r] : aN0[r];
                float vH = ms ? aH1[r] : aH0[r];
                int row = rbase + ms * 16 + qm * 4 + r;
                float rg = sigm(vR + brz);
                float z  = sigm(vZ + bzz);
                float ng = tanh_fast(vN + bnx + rg * (vH + bnh));
                float h  = bf2f(X[(size_t)row * 256 + 128 + colg]);
                float h0 = fmaxf((1.f - z) * ng + z * h, 0.f);
                if (row < N) {
                    if (isb) ((u16*)out)[(size_t)row * 128 + colg] = f2bf(h0);
                    else     ((float*)out)[(size_t)row * 128 + colg] = h0;
                }
                ss[ms * 4 + r] += h0 * h0;
            }
        }
    }

    // 64-col partial sumsq per row -> ssb[g*NpadX + row]
    #pragma unroll
    for (int i = 0; i < 8; ++i) {
        float s = ss[i];
        s += __shfl_xor(s, 1, 64);
        s += __shfl_xor(s, 2, 64);
        s += __shfl_xor(s, 4, 64);
        s += __shfl_xor(s, 8, 64);
        ss[i] = s;
    }
    if (qr == 0) {
        #pragma unroll
        for (int ms = 0; ms < 2; ++ms)
            #pragma unroll
            for (int r = 0; r < 4; ++r)
                ssb[(size_t)g * NpadX + rbase + ms * 16 + qm * 4 + r] = ss[ms * 4 + r];
    }
}

// K4 pass 2: in-place row L2-normalize of out using the two 64-col partials.
__global__ __launch_bounds__(256) void k_norm(
    void* __restrict__ out, const float* __restrict__ ssb,
    const int* __restrict__ flag, int N, int NpadX)
{
    int isb = flag[0];
    int tid = threadIdx.x;
    int wave = tid >> 6, lane = tid & 63;
    int row = blockIdx.x * 16 + wave * 4 + (lane >> 4);
    if (row >= N) return;
    int c8 = (lane & 15) * 8;
    float s = ssb[row] + ssb[(size_t)NpadX + row];
    float iv = 1.f / fmaxf(sqrtf(s), 1e-12f);
    if (isb) {
        u16* p = (u16*)out + (size_t)row * 128 + c8;
        bf16x8 v = *(const bf16x8*)p;
        bf16x8 o;
        #pragma unroll
        for (int j = 0; j < 8; ++j) o[j] = (short)f2bf(bf2f((u16)v[j]) * iv);
        *(bf16x8*)p = o;
    } else {
        float* p = (float*)out + (size_t)row * 128 + c8;
        float4 v0 = *(float4*)p, v1 = *(float4*)(p + 4);
        v0.x *= iv; v0.y *= iv; v0.z *= iv; v0.w *= iv;
        v1.x *= iv; v1.y *= iv; v1.z *= iv; v1.w *= iv;
        *(float4*)p = v0; *(float4*)(p + 4) = v1;
    }
}

extern "C" void kernel_launch(void* const* d_in, const int* in_sizes, int n_in,
                              void* d_out, int out_size, void* d_ws, size_t ws_size,
                              hipStream_t stream) {
    const void* ent     = d_in[0];
    const void* bias    = d_in[2];
    const void* onorm   = d_in[3];
    const void* W       = d_in[4];
    const void* w_ih    = d_in[5];
    const void* w_hh    = d_in[6];
    const void* b_ih    = d_in[7];
    const void* b_hh    = d_in[8];
    const void* node_id = d_in[9];
    const int*  esrc    = (const int*)d_in[10];
    const int*  edst    = (const int*)d_in[11];

    int N = in_sizes[2] / D;     // 100000
    int E = in_sizes[10];        // 1600000
    int NpadX = ((N + 255) / 256) * 256;   // X padded to the 256-row chunk grid

    char* ws = (char*)d_ws;
    size_t o = 0;
    int*   flag = (int*)(ws + o);   o += 64;
    u16*   WTb  = (u16*)(ws + o);   o += 16384u * 2;
    u16*   Wihb = (u16*)(ws + o);   o += 98304u * 2;
    u16*   Whhb = (u16*)(ws + o);   o += 49152u * 2;
    float* bif  = (float*)(ws + o); o += 2048;
    float* bhf  = (float*)(ws + o); o += 2048;
    u16*   X    = (u16*)(ws + o);   o += (size_t)NpadX * 256 * 2;
    u16*   hW   = (u16*)(ws + o);   o += (size_t)N * D * 2;
    int*   cnt  = (int*)(ws + o);   o += (size_t)N * 4;
    int*   rowstart = (int*)(ws + o); o += ((size_t)N + 16) * 4;
    int*   part = (int*)(ws + o);   o += 4096;
    int*   sorted_src = (int*)(ws + o); o += (size_t)E * 4;
    int*   cursor = cnt;
    // sorted_src is dead after k_seg; reuse its space for the sumsq partials
    float* ssb = (float*)sorted_src;       // needs 2*NpadX*4 = ~0.8 MB << E*4

    int nb = (N + 1023) / 1024;
    int nchunk = NpadX / 256;

    k_detect<<<1, 64, 0, stream>>>(ent, node_id, flag);
    k_prep<<<643, 256, 0, stream>>>(w_ih, w_hh, b_ih, b_hh, W, flag,
                                    WTb, Wihb, Whhb, bif, bhf);
    k_zero<<<(N + 255) / 256, 256, 0, stream>>>(cnt, N);
    k_gmm_mfma<<<(N + 63) / 64, 256, 0, stream>>>(ent, node_id, WTb, hW, flag, N);
    k_hist<<<(E + 255) / 256, 256, 0, stream>>>(edst, cnt, E);
    k_scan1<<<nb, 256, 0, stream>>>(cnt, rowstart, part, N);
    k_scan2<<<1, 128, 0, stream>>>(part, rowstart, nb, N);
    k_scan3<<<(N + 255) / 256, 256, 0, stream>>>(rowstart, part, cursor, N);
    k_fill<<<(E + 255) / 256, 256, 0, stream>>>(esrc, edst, cursor, sorted_src, E);
    k_seg<<<(N + 3) / 4, 256, 0, stream>>>(hW, rowstart, sorted_src, onorm, bias, X, flag, N);
    k_gru_mfma<<<nchunk * 2, 512, 0, stream>>>(X, Wihb, Whhb, bif, bhf, d_out, ssb, flag, N, NpadX);
    k_norm<<<(N + 15) / 16, 256, 0, stream>>>(d_out, ssb, flag, N, NpadX);
}

// Round 7
// 508.095 us; speedup vs baseline: 1.4662x; 1.2250x over previous
//
#include <hip/hip_runtime.h>
#include <hip/hip_bf16.h>

#define D 128

typedef unsigned short u16;
typedef unsigned int   u32;
typedef unsigned long long u64;
typedef short bf16x8 __attribute__((ext_vector_type(8)));
typedef float f32x4  __attribute__((ext_vector_type(4)));

__device__ __forceinline__ float bf2f(u16 u) {
    union { u32 i; float f; } v; v.i = ((u32)u) << 16; return v.f;
}
__device__ __forceinline__ float bflo(u32 p) {
    union { u32 i; float f; } v; v.i = p << 16; return v.f;
}
__device__ __forceinline__ float bfhi(u32 p) {
    union { u32 i; float f; } v; v.i = p & 0xffff0000u; return v.f;
}
__device__ __forceinline__ u16 f2bf(float f) {
    union { float f; u32 i; } v; v.f = f;
    return (u16)((v.i + 0x7fffu + ((v.i >> 16) & 1u)) >> 16);
}
__device__ __forceinline__ float ldf(const void* p, long i, int isb) {
    return isb ? bf2f(((const u16*)p)[i]) : ((const float*)p)[i];
}

__device__ __forceinline__ float sigm(float x) { return 1.0f / (1.0f + __expf(-x)); }
__device__ __forceinline__ float tanh_fast(float x) {
    float a = fabsf(x);
    float t = __expf(-2.0f * a);
    float r = (1.0f - t) / (1.0f + t);
    return copysignf(r, x);
}

__global__ void DRlocal_net_79173427135059_kernel() {}

// K-1: runtime dtype detection + zero the bucket histogram.
__global__ __launch_bounds__(64) void k_detect(const void* ent, const void* nid,
                                               int* flag, int* bhist) {
    int lane = threadIdx.x;
    for (int i = lane; i < 512; i += 64) bhist[i] = 0;
    float a = fabsf(bf2f(((const u16*)ent)[lane]));
    bool sane = (a >= 9.765625e-4f && a <= 64.0f);
    u64 m = __ballot(sane);
    u32 w = ((const u32*)nid)[lane];
    bool oddzero = ((lane & 1) == 0) || (w == 0u);
    u64 m2 = __ballot(oddzero);
    if (lane == 0) {
        flag[0] = (__popcll(m) >= 48) ? 1 : 0;
        flag[1] = (m2 == ~0ull) ? 1 : 0;
    }
}

// K0: WTb[j][k] = bf16(W[k][j]); GRU weights -> bf16 as-is; biases -> f32.
__global__ __launch_bounds__(256) void k_prep(
    const void* __restrict__ w_ih, const void* __restrict__ w_hh,
    const void* __restrict__ b_ih, const void* __restrict__ b_hh,
    const void* __restrict__ W, const int* __restrict__ flag,
    u16* __restrict__ WTb, u16* __restrict__ Wihb, u16* __restrict__ Whhb,
    float* __restrict__ bif, float* __restrict__ bhf)
{
    int isb = flag[0];
    int t = blockIdx.x * 256 + threadIdx.x;
    if (t < 16384) {
        int k = t >> 7, j = t & 127;
        u16 v = isb ? ((const u16*)W)[t] : f2bf(((const float*)W)[t]);
        WTb[j * 128 + k] = v;
        return;
    }
    int u = t - 16384;
    if (u < 98304) { Wihb[u] = isb ? ((const u16*)w_ih)[u] : f2bf(((const float*)w_ih)[u]); return; }
    int v = u - 98304;
    if (v < 49152) { Whhb[v] = isb ? ((const u16*)w_hh)[v] : f2bf(((const float*)w_hh)[v]); return; }
    int b = v - 49152;
    if (b < 384) { bif[b] = ldf(b_ih, b, isb); return; }
    int c = b - 384;
    if (c < 384) { bhf[c] = ldf(b_hh, c, isb); return; }
}

// K1: hW = gather(ent, node_id) @ W via MFMA. 64 nodes/block, wave = one 16-row m-tile.
__global__ __launch_bounds__(256) void k_gmm_mfma(
    const void* __restrict__ ent, const void* __restrict__ node_id,
    const u16* __restrict__ WTb, u16* __restrict__ hW,
    const int* __restrict__ flag, int N)
{
    int isb = flag[0], i64 = flag[1];
    int tid = threadIdx.x;
    int wave = tid >> 6, lane = tid & 63;
    int qm = lane >> 4, qr = lane & 15;
    int row0 = blockIdx.x * 64 + wave * 16;

    int rowA = row0 + qr; if (rowA >= N) rowA = N - 1;
    long nid = i64 ? (long)((const long long*)node_id)[rowA]
                   : (long)((const int*)node_id)[rowA];

    bf16x8 a[4];
    if (isb) {
        const u16* ep = (const u16*)ent + nid * 128 + qm * 8;
        #pragma unroll
        for (int s = 0; s < 4; ++s) a[s] = *(const bf16x8*)(ep + s * 32);
    } else {
        const float* ep = (const float*)ent + nid * 128 + qm * 8;
        #pragma unroll
        for (int s = 0; s < 4; ++s) {
            float4 f0 = *(const float4*)(ep + s * 32);
            float4 f1 = *(const float4*)(ep + s * 32 + 4);
            bf16x8 t;
            t[0] = (short)f2bf(f0.x); t[1] = (short)f2bf(f0.y);
            t[2] = (short)f2bf(f0.z); t[3] = (short)f2bf(f0.w);
            t[4] = (short)f2bf(f1.x); t[5] = (short)f2bf(f1.y);
            t[6] = (short)f2bf(f1.z); t[7] = (short)f2bf(f1.w);
            a[s] = t;
        }
    }

    int r0 = row0 + qm * 4;
    #pragma unroll
    for (int f = 0; f < 8; ++f) {
        f32x4 acc = {0.f, 0.f, 0.f, 0.f};
        const u16* wp = WTb + (size_t)(f * 16 + qr) * 128 + qm * 8;
        #pragma unroll
        for (int s = 0; s < 4; ++s) {
            bf16x8 b = *(const bf16x8*)(wp + s * 32);
            acc = __builtin_amdgcn_mfma_f32_16x16x32_bf16(a[s], b, acc, 0, 0, 0);
        }
        int col = f * 16 + qr;
        #pragma unroll
        for (int r = 0; r < 4; ++r) {
            int row = r0 + r;
            if (row < N) hW[(size_t)row * 128 + col] = f2bf(acc[r]);
        }
    }
}

// ---- Bucket CSR build (replaces zero/hist/scan1/scan2/scan3/fill) ----
// Buckets of (1<<bshift) nodes. All scatter writes become block-local.

// B1: per-bucket edge histogram, LDS-aggregated.
__global__ __launch_bounds__(256) void k_bhist(
    const int* __restrict__ edst, int* __restrict__ bhist,
    int E, int NB, int bshift)
{
    __shared__ int lcnt[512];
    int t = threadIdx.x;
    int e0 = blockIdx.x * 8192;
    for (int i = t; i < NB; i += 256) lcnt[i] = 0;
    __syncthreads();
    for (int i = t; i < 8192; i += 256) {
        int e = e0 + i;
        if (e < E) atomicAdd(&lcnt[edst[e] >> bshift], 1);
    }
    __syncthreads();
    for (int i = t; i < NB; i += 256) {
        int c = lcnt[i];
        if (c) atomicAdd(&bhist[i], c);
    }
}

// B2: scan NB bucket counts -> bstart/bcur; terminal markers.
__global__ __launch_bounds__(512) void k_bscan(
    const int* __restrict__ bhist, int* __restrict__ bstart,
    int* __restrict__ bcur, int* __restrict__ rowstart,
    int NB, int N, int E)
{
    __shared__ int sh[512];
    int t = threadIdx.x;
    int v = (t < NB) ? bhist[t] : 0;
    sh[t] = v;
    __syncthreads();
    #pragma unroll
    for (int off = 1; off < 512; off <<= 1) {
        int x = (t >= off) ? sh[t - off] : 0;
        __syncthreads();
        sh[t] += x;
        __syncthreads();
    }
    int excl = sh[t] - v;
    if (t < NB) { bstart[t] = excl; bcur[t] = excl; }
    if (t == 0) { bstart[NB] = E; rowstart[N] = E; }
}

// B3: block-aggregated scatter of (src,dst) pairs into bucket-ordered ebuf.
// Per block: LDS bucket counts -> ONE global reservation atomic per bucket ->
// scatter to contiguous per-bucket runs. Write amplification ~1x (was 16x).
__global__ __launch_bounds__(256) void k_afill(
    const int* __restrict__ esrc, const int* __restrict__ edst,
    int* __restrict__ bcur, u64* __restrict__ ebuf,
    int E, int NB, int bshift)
{
    __shared__ int lcnt[512];
    int t = threadIdx.x;
    int e0 = blockIdx.x * 8192;
    for (int i = t; i < NB; i += 256) lcnt[i] = 0;
    __syncthreads();
    for (int i = t; i < 8192; i += 256) {
        int e = e0 + i;
        if (e < E) atomicAdd(&lcnt[edst[e] >> bshift], 1);
    }
    __syncthreads();
    for (int b = t; b < NB; b += 256) {
        int c = lcnt[b];
        lcnt[b] = c ? atomicAdd(&bcur[b], c) : 0;
    }
    __syncthreads();
    for (int i = t; i < 8192; i += 256) {
        int e = e0 + i;
        if (e < E) {
            int d = edst[e];
            int pos = atomicAdd(&lcnt[d >> bshift], 1);
            ebuf[pos] = ((u64)(u32)esrc[e] << 32) | (u32)d;
        }
    }
}

// B4: one block per bucket. LDS node-histogram + scan -> rowstart; then fill
// sorted_src. Output range (~16 KB) is contiguous -> single line write-backs.
__global__ __launch_bounds__(256) void k_bfill(
    const u64* __restrict__ ebuf, const int* __restrict__ bstart,
    int* __restrict__ rowstart, int* __restrict__ sorted_src,
    int N, int bshift)
{
    __shared__ int lcnt[1024];
    __shared__ int lscan[256];
    int b = blockIdx.x, t = threadIdx.x;
    int nodes = 1 << bshift;          // 256..1024
    int per = nodes >> 8;             // 1..4
    int base = b << bshift;
    int beg = bstart[b], end = bstart[b + 1];

    for (int i = t; i < nodes; i += 256) lcnt[i] = 0;
    __syncthreads();
    for (int i = beg + t; i < end; i += 256) {
        int d = (int)(u32)ebuf[i];
        atomicAdd(&lcnt[d - base], 1);
    }
    __syncthreads();

    int myv[4]; int mysum = 0;
    #pragma unroll
    for (int j = 0; j < 4; ++j) {
        myv[j] = (j < per) ? lcnt[t * per + j] : 0;
        mysum += myv[j];
    }
    lscan[t] = mysum;
    __syncthreads();
    #pragma unroll
    for (int off = 1; off < 256; off <<= 1) {
        int x = (t >= off) ? lscan[t - off] : 0;
        __syncthreads();
        lscan[t] += x;
        __syncthreads();
    }
    int run = beg + lscan[t] - mysum;
    #pragma unroll
    for (int j = 0; j < 4; ++j) {
        if (j < per) {
            int idx = t * per + j;
            int node = base + idx;
            if (node < N) rowstart[node] = run;
            lcnt[idx] = run;         // becomes the fill cursor
            run += myv[j];
        }
    }
    __syncthreads();
    for (int i = beg + t; i < end; i += 256) {
        u64 p = ebuf[i];
        int d = (int)(u32)p;
        int pos = atomicAdd(&lcnt[d - base], 1);
        sorted_src[pos] = (int)(p >> 32);
    }
}

// K3: segment sum -> X[:,0:128] = bf16(agg*out_norm); also X[:,128:256] = e_r_bias.
__global__ __launch_bounds__(256) void k_seg(
    const u16* __restrict__ hW, const int* __restrict__ rowstart,
    const int* __restrict__ sorted_src, const void* __restrict__ onorm,
    const void* __restrict__ bias, u16* __restrict__ X,
    const int* __restrict__ flag, int N)
{
    int isb = flag[0];
    int tid = threadIdx.x;
    int node = blockIdx.x * 4 + (tid >> 6);
    int lane = tid & 63;
    if (node >= N) return;
    int beg = rowstart[node], end = rowstart[node + 1];
    const u32* hw2 = (const u32*)hW;
    float a0 = 0.f, a1 = 0.f;
    int e = beg;
    for (; e + 8 <= end; e += 8) {
        int sI[8]; u32 vI[8];
        #pragma unroll
        for (int i = 0; i < 8; ++i) sI[i] = sorted_src[e + i];
        #pragma unroll
        for (int i = 0; i < 8; ++i) vI[i] = hw2[(size_t)sI[i] * 64 + lane];
        #pragma unroll
        for (int i = 0; i < 8; ++i) { a0 += bflo(vI[i]); a1 += bfhi(vI[i]); }
    }
    for (; e + 4 <= end; e += 4) {
        int s0 = sorted_src[e], s1 = sorted_src[e + 1];
        int s2 = sorted_src[e + 2], s3 = sorted_src[e + 3];
        u32 v0 = hw2[(size_t)s0 * 64 + lane];
        u32 v1 = hw2[(size_t)s1 * 64 + lane];
        u32 v2 = hw2[(size_t)s2 * 64 + lane];
        u32 v3 = hw2[(size_t)s3 * 64 + lane];
        a0 += bflo(v0) + bflo(v1) + bflo(v2) + bflo(v3);
        a1 += bfhi(v0) + bfhi(v1) + bfhi(v2) + bfhi(v3);
    }
    for (; e < end; ++e) {
        u32 v = hw2[(size_t)sorted_src[e] * 64 + lane];
        a0 += bflo(v); a1 += bfhi(v);
    }
    float on = ldf(onorm, node, isb);
    u32 p = ((u32)f2bf(a1 * on) << 16) | (u32)f2bf(a0 * on);
    ((u32*)X)[(size_t)node * 128 + lane] = p;
    u32 pb;
    if (isb) pb = ((const u32*)bias)[(size_t)node * 64 + lane];
    else {
        const float* bp = (const float*)bias + (size_t)node * 128 + lane * 2;
        pb = ((u32)f2bf(bp[1]) << 16) | (u32)f2bf(bp[0]);
    }
    ((u32*)X)[(size_t)node * 128 + 64 + lane] = pb;
}

// K4 v6, pass 1: LDS-weight-resident MFMA GRU, column-split (unchanged, proven).
__global__ __launch_bounds__(512, 2) void k_gru_mfma(
    const u16* __restrict__ X, const u16* __restrict__ Wih,
    const u16* __restrict__ Whh, const float* __restrict__ bif,
    const float* __restrict__ bhf, void* __restrict__ out,
    float* __restrict__ ssb,
    const int* __restrict__ flag, int N, int NpadX)
{
    __shared__ alignas(16) char smem[147456];   // [3][64][256]ih + [3][64][128]hh
    int isb = flag[0];
    int tid = threadIdx.x;
    int wave = tid >> 6, lane = tid & 63;
    int qm = lane >> 4, qr = lane & 15;
    int g = blockIdx.x & 1;                 // column group: cols [g*64, g*64+64)
    int chunk = blockIdx.x >> 1;
    int g64 = g * 64;

    for (int t = tid; t < 6144; t += 512) {     // Wih region: 98304 B
        int L = t * 16;
        int kb = L & 511;
        int c  = (L >> 9) & 63;
        int gi = L >> 15;
        int src = (gi * 128 + g64 + c) * 512 + kb;
        int dst = L ^ ((c & 7) << 4);
        *(bf16x8*)(smem + dst) = *(const bf16x8*)((const char*)Wih + src);
    }
    for (int t = tid; t < 3072; t += 512) {     // Whh region: 49152 B @ 98304
        int L = t * 16;
        int kb = L & 255;
        int c  = (L >> 8) & 63;
        int gi = L >> 14;
        int src = (gi * 128 + g64 + c) * 256 + kb;
        int dst = 98304 + (L ^ ((c & 7) << 4));
        *(bf16x8*)(smem + dst) = *(const bf16x8*)((const char*)Whh + src);
    }
    __syncthreads();

    int rbase = chunk * 256 + wave * 32;

    bf16x8 aA[8], aB[8];
    {
        const u16* x0 = X + (size_t)(rbase + qr) * 256 + qm * 8;
        #pragma unroll
        for (int s = 0; s < 8; ++s) aA[s] = *(const bf16x8*)(x0 + s * 32);
        const u16* x1 = x0 + 16 * 256;
        #pragma unroll
        for (int s = 0; s < 8; ++s) aB[s] = *(const bf16x8*)(x1 + s * 32);
    }

    float ss[8] = {0.f, 0.f, 0.f, 0.f, 0.f, 0.f, 0.f, 0.f};

    #pragma unroll 1
    for (int sl = 0; sl < 4; ++sl) {
        int colIdx = sl * 16 + qr;
        int colg = g64 + colIdx;
        int sw = (qr & 7) << 4;
        int cbI = colIdx * 512 + qm * 16;
        int cbH = colIdx * 256 + qm * 16;

        f32x4 zz = {0.f, 0.f, 0.f, 0.f};
        f32x4 aR0 = zz, aR1 = zz, aZ0 = zz, aZ1 = zz;
        f32x4 aN0 = zz, aN1 = zz, aH0 = zz, aH1 = zz;

        {   // r gate
            bf16x8 w[12];
            #pragma unroll
            for (int s = 0; s < 8; ++s)
                w[s] = *(const bf16x8*)(smem + ((cbI + s * 64) ^ sw));
            #pragma unroll
            for (int s = 0; s < 4; ++s)
                w[8 + s] = *(const bf16x8*)(smem + 98304 + ((cbH + s * 64) ^ sw));
            #pragma unroll
            for (int s = 0; s < 8; ++s) {
                aR0 = __builtin_amdgcn_mfma_f32_16x16x32_bf16(aA[s], w[s], aR0, 0, 0, 0);
                aR1 = __builtin_amdgcn_mfma_f32_16x16x32_bf16(aB[s], w[s], aR1, 0, 0, 0);
            }
            #pragma unroll
            for (int s = 0; s < 4; ++s) {
                aR0 = __builtin_amdgcn_mfma_f32_16x16x32_bf16(aA[4 + s], w[8 + s], aR0, 0, 0, 0);
                aR1 = __builtin_amdgcn_mfma_f32_16x16x32_bf16(aB[4 + s], w[8 + s], aR1, 0, 0, 0);
            }
        }
        {   // z gate
            bf16x8 w[12];
            #pragma unroll
            for (int s = 0; s < 8; ++s)
                w[s] = *(const bf16x8*)(smem + 32768 + ((cbI + s * 64) ^ sw));
            #pragma unroll
            for (int s = 0; s < 4; ++s)
                w[8 + s] = *(const bf16x8*)(smem + 98304 + 16384 + ((cbH + s * 64) ^ sw));
            #pragma unroll
            for (int s = 0; s < 8; ++s) {
                aZ0 = __builtin_amdgcn_mfma_f32_16x16x32_bf16(aA[s], w[s], aZ0, 0, 0, 0);
                aZ1 = __builtin_amdgcn_mfma_f32_16x16x32_bf16(aB[s], w[s], aZ1, 0, 0, 0);
            }
            #pragma unroll
            for (int s = 0; s < 4; ++s) {
                aZ0 = __builtin_amdgcn_mfma_f32_16x16x32_bf16(aA[4 + s], w[8 + s], aZ0, 0, 0, 0);
                aZ1 = __builtin_amdgcn_mfma_f32_16x16x32_bf16(aB[4 + s], w[8 + s], aZ1, 0, 0, 0);
            }
        }
        {   // n gate
            bf16x8 w[12];
            #pragma unroll
            for (int s = 0; s < 8; ++s)
                w[s] = *(const bf16x8*)(smem + 65536 + ((cbI + s * 64) ^ sw));
            #pragma unroll
            for (int s = 0; s < 4; ++s)
                w[8 + s] = *(const bf16x8*)(smem + 98304 + 32768 + ((cbH + s * 64) ^ sw));
            #pragma unroll
            for (int s = 0; s < 8; ++s) {
                aN0 = __builtin_amdgcn_mfma_f32_16x16x32_bf16(aA[s], w[s], aN0, 0, 0, 0);
                aN1 = __builtin_amdgcn_mfma_f32_16x16x32_bf16(aB[s], w[s], aN1, 0, 0, 0);
            }
            #pragma unroll
            for (int s = 0; s < 4; ++s) {
                aH0 = __builtin_amdgcn_mfma_f32_16x16x32_bf16(aA[4 + s], w[8 + s], aH0, 0, 0, 0);
                aH1 = __builtin_amdgcn_mfma_f32_16x16x32_bf16(aB[4 + s], w[8 + s], aH1, 0, 0, 0);
            }
        }

        float brz = bif[colg] + bhf[colg];
        float bzz = bif[128 + colg] + bhf[128 + colg];
        float bnx = bif[256 + colg];
        float bnh = bhf[256 + colg];

        #pragma unroll
        for (int ms = 0; ms < 2; ++ms) {
            #pragma unroll
            for (int r = 0; r < 4; ++r) {
                float vR = ms ? aR1[r] : aR0[r];
                float vZ = ms ? aZ1[r] : aZ0[r];
                float vN = ms ? aN1[r] : aN0[r];
                float vH = ms ? aH1[r] : aH0[r];
                int row = rbase + ms * 16 + qm * 4 + r;
                float rg = sigm(vR + brz);
                float z  = sigm(vZ + bzz);
                float ng = tanh_fast(vN + bnx + rg * (vH + bnh));
                float h  = bf2f(X[(size_t)row * 256 + 128 + colg]);
                float h0 = fmaxf((1.f - z) * ng + z * h, 0.f);
                if (row < N) {
                    if (isb) ((u16*)out)[(size_t)row * 128 + colg] = f2bf(h0);
                    else     ((float*)out)[(size_t)row * 128 + colg] = h0;
                }
                ss[ms * 4 + r] += h0 * h0;
            }
        }
    }

    #pragma unroll
    for (int i = 0; i < 8; ++i) {
        float s = ss[i];
        s += __shfl_xor(s, 1, 64);
        s += __shfl_xor(s, 2, 64);
        s += __shfl_xor(s, 4, 64);
        s += __shfl_xor(s, 8, 64);
        ss[i] = s;
    }
    if (qr == 0) {
        #pragma unroll
        for (int ms = 0; ms < 2; ++ms)
            #pragma unroll
            for (int r = 0; r < 4; ++r)
                ssb[(size_t)g * NpadX + rbase + ms * 16 + qm * 4 + r] = ss[ms * 4 + r];
    }
}

// K4 pass 2: in-place row L2-normalize of out using the two 64-col partials.
__global__ __launch_bounds__(256) void k_norm(
    void* __restrict__ out, const float* __restrict__ ssb,
    const int* __restrict__ flag, int N, int NpadX)
{
    int isb = flag[0];
    int tid = threadIdx.x;
    int wave = tid >> 6, lane = tid & 63;
    int row = blockIdx.x * 16 + wave * 4 + (lane >> 4);
    if (row >= N) return;
    int c8 = (lane & 15) * 8;
    float s = ssb[row] + ssb[(size_t)NpadX + row];
    float iv = 1.f / fmaxf(sqrtf(s), 1e-12f);
    if (isb) {
        u16* p = (u16*)out + (size_t)row * 128 + c8;
        bf16x8 v = *(const bf16x8*)p;
        bf16x8 o;
        #pragma unroll
        for (int j = 0; j < 8; ++j) o[j] = (short)f2bf(bf2f((u16)v[j]) * iv);
        *(bf16x8*)p = o;
    } else {
        float* p = (float*)out + (size_t)row * 128 + c8;
        float4 v0 = *(float4*)p, v1 = *(float4*)(p + 4);
        v0.x *= iv; v0.y *= iv; v0.z *= iv; v0.w *= iv;
        v1.x *= iv; v1.y *= iv; v1.z *= iv; v1.w *= iv;
        *(float4*)p = v0; *(float4*)(p + 4) = v1;
    }
}

extern "C" void kernel_launch(void* const* d_in, const int* in_sizes, int n_in,
                              void* d_out, int out_size, void* d_ws, size_t ws_size,
                              hipStream_t stream) {
    const void* ent     = d_in[0];
    const void* bias    = d_in[2];
    const void* onorm   = d_in[3];
    const void* W       = d_in[4];
    const void* w_ih    = d_in[5];
    const void* w_hh    = d_in[6];
    const void* b_ih    = d_in[7];
    const void* b_hh    = d_in[8];
    const void* node_id = d_in[9];
    const int*  esrc    = (const int*)d_in[10];
    const int*  edst    = (const int*)d_in[11];

    int N = in_sizes[2] / D;     // 100000
    int E = in_sizes[10];        // 1600000
    int NpadX = ((N + 255) / 256) * 256;

    // bucket geometry: <=512 buckets, 256..1024 nodes each
    int bshift = 8;
    while ((((N - 1) >> bshift) + 1) > 512) bshift++;
    int NB = ((N - 1) >> bshift) + 1;

    char* ws = (char*)d_ws;
    size_t o = 0;
    int*   flag = (int*)(ws + o);   o += 64;
    u16*   WTb  = (u16*)(ws + o);   o += 16384u * 2;
    u16*   Wihb = (u16*)(ws + o);   o += 98304u * 2;
    u16*   Whhb = (u16*)(ws + o);   o += 49152u * 2;
    float* bif  = (float*)(ws + o); o += 2048;
    float* bhf  = (float*)(ws + o); o += 2048;
    u16*   X    = (u16*)(ws + o);   o += (size_t)NpadX * 256 * 2;
    u16*   hW   = (u16*)(ws + o);   o += (size_t)N * D * 2;
    int*   bhist = (int*)(ws + o);  o += 512 * 4;
    int*   bstart = (int*)(ws + o); o += 514 * 4;
    int*   bcur  = (int*)(ws + o);  o += 512 * 4;
    int*   rowstart = (int*)(ws + o); o += ((size_t)N + 16) * 4;
    int*   sorted_src = (int*)(ws + o); o += (size_t)E * 4;
    // ebuf aliases X: dead until k_seg writes X (after k_bfill). 8B-aligned.
    u64*   ebuf = (u64*)X;
    // sorted_src is dead after k_seg; reuse for the sumsq partials.
    float* ssb = (float*)sorted_src;

    int nchunk = NpadX / 256;
    int nA = (E + 8191) / 8192;

    k_detect<<<1, 64, 0, stream>>>(ent, node_id, flag, bhist);
    k_prep<<<643, 256, 0, stream>>>(w_ih, w_hh, b_ih, b_hh, W, flag,
                                    WTb, Wihb, Whhb, bif, bhf);
    k_gmm_mfma<<<(N + 63) / 64, 256, 0, stream>>>(ent, node_id, WTb, hW, flag, N);
    k_bhist<<<nA, 256, 0, stream>>>(edst, bhist, E, NB, bshift);
    k_bscan<<<1, 512, 0, stream>>>(bhist, bstart, bcur, rowstart, NB, N, E);
    k_afill<<<nA, 256, 0, stream>>>(esrc, edst, bcur, ebuf, E, NB, bshift);
    k_bfill<<<NB, 256, 0, stream>>>(ebuf, bstart, rowstart, sorted_src, N, bshift);
    k_seg<<<(N + 3) / 4, 256, 0, stream>>>(hW, rowstart, sorted_src, onorm, bias, X, flag, N);
    k_gru_mfma<<<nchunk * 2, 512, 0, stream>>>(X, Wihb, Whhb, bif, bhf, d_out, ssb, flag, N, NpadX);
    k_norm<<<(N + 15) / 16, 256, 0, stream>>>(d_out, ssb, flag, N, NpadX);
}